// Round 9
// baseline (51.186 us; speedup 1.0000x reference)
//
#include <hip/hip_runtime.h>
#include <math.h>

// HyperConnections: out[(b*S+t), n, d] = sum_s M[t][s] * in[(b*S+s), n, d]
// M[t][s] = sinkhorn(H_res/tau)[s][t] + softmax(H_post)[t] * softmax(H_pre)[s]
//
// B=4, S=4, N=2048, D=1024, fp32. Memory-bound: 128 MiB in + 128 MiB out.
// Barrier-free: each WAVE computes the 4x4 Sinkhorn in parallel across 16
// lanes (lane i*4+j owns element (i,j); row/col LSE reductions via
// __shfl_xor 1,2 and 4,8; lanes 16-63 hold replicas). No LDS, no
// __syncthreads, no per-block bubble. Batch loads are issued up front so the
// Sinkhorn chain overlaps HBM latency.

#define HC_TAU 0.05f
#define HC_ITERS 10

typedef float f4 __attribute__((ext_vector_type(4)));

// N*D/4 float4 elements per stream = 2048*1024/4 = 524288 = 2^19
constexpr int ND4 = (2048 * 1024) / 4;
constexpr size_t BATCH_STRIDE = (size_t)4 * ND4;   // 4 streams per batch

__global__ __launch_bounds__(256) void hc_mix_kernel(
    const f4* __restrict__ in, f4* __restrict__ out,
    const float* __restrict__ Hres, const float* __restrict__ Hpre,
    const float* __restrict__ Hpost)
{
    const size_t r = (size_t)blockIdx.x * 256 + threadIdx.x;   // 0 .. ND4-1

    // ---- issue all 16 input loads up front (4 batches x 4 streams) ----
    f4 q[4][4];
    #pragma unroll
    for (int b = 0; b < 4; ++b) {
        const f4* pb = in + (size_t)b * BATCH_STRIDE + r;
        #pragma unroll
        for (int s = 0; s < 4; ++s)
            q[b][s] = pb[(size_t)s * ND4];
    }

    // ---- wave-parallel Sinkhorn: lane idx = i*4+j owns Z[i][j] ----
    const int lane = threadIdx.x & 63;
    const int idx  = lane & 15;              // replicas in lanes 16-63
    const float Zl = Hres[idx] * (1.0f / HC_TAU);

    float ui = 0.f, vj = 0.f;
    for (int it = 0; it < HC_ITERS; ++it) {
        // u[i] = -lse_j(Z[i][j] + v[j])  -- reduce within row group (xor 1,2)
        float x = Zl + vj;
        float m = fmaxf(x, __shfl_xor(x, 1));
        m = fmaxf(m, __shfl_xor(m, 2));
        float e = __expf(x - m);
        float s = e + __shfl_xor(e, 1);
        s += __shfl_xor(s, 2);
        ui = -(m + __logf(s));
        // v[j] = -lse_i(Z[i][j] + u[i])  -- reduce within col group (xor 4,8)
        float y = Zl + ui;
        float m2 = fmaxf(y, __shfl_xor(y, 4));
        m2 = fmaxf(m2, __shfl_xor(m2, 8));
        float e2 = __expf(y - m2);
        float s2 = e2 + __shfl_xor(e2, 4);
        s2 += __shfl_xor(s2, 8);
        vj = -(m2 + __logf(s2));
    }
    const float P = __expf(Zl + ui + vj);    // h_res[i][j] on lane i*4+j

    // ---- softmax(H_pre), softmax(H_post): tiny, redundant per lane ----
    float hp[4], bt[4];
    {
        float a0 = Hpre[0], a1 = Hpre[1], a2 = Hpre[2], a3 = Hpre[3];
        float m = fmaxf(fmaxf(a0, a1), fmaxf(a2, a3));
        hp[0] = __expf(a0 - m); hp[1] = __expf(a1 - m);
        hp[2] = __expf(a2 - m); hp[3] = __expf(a3 - m);
        float inv = 1.0f / (hp[0] + hp[1] + hp[2] + hp[3]);
        hp[0] *= inv; hp[1] *= inv; hp[2] *= inv; hp[3] *= inv;

        float b0 = Hpost[0], b1 = Hpost[1], b2 = Hpost[2], b3 = Hpost[3];
        m = fmaxf(fmaxf(b0, b1), fmaxf(b2, b3));
        bt[0] = __expf(b0 - m); bt[1] = __expf(b1 - m);
        bt[2] = __expf(b2 - m); bt[3] = __expf(b3 - m);
        inv = 1.0f / (bt[0] + bt[1] + bt[2] + bt[3]);
        bt[0] *= inv; bt[1] *= inv; bt[2] *= inv; bt[3] *= inv;
    }

    // ---- gather full M into every lane: M[t][s] = P@lane(s*4+t) + bt[t]*hp[s]
    float M[16];
    #pragma unroll
    for (int t = 0; t < 4; ++t)
        #pragma unroll
        for (int s = 0; s < 4; ++s)
            M[t * 4 + s] = __shfl(P, s * 4 + t) + bt[t] * hp[s];

    // ---- compute + store all 16 outputs ----
    #pragma unroll
    for (int b = 0; b < 4; ++b) {
        f4* po = out + (size_t)b * BATCH_STRIDE + r;
        #pragma unroll
        for (int t = 0; t < 4; ++t) {
            f4 o;
            o.x = M[4*t+0]*q[b][0].x + M[4*t+1]*q[b][1].x + M[4*t+2]*q[b][2].x + M[4*t+3]*q[b][3].x;
            o.y = M[4*t+0]*q[b][0].y + M[4*t+1]*q[b][1].y + M[4*t+2]*q[b][2].y + M[4*t+3]*q[b][3].y;
            o.z = M[4*t+0]*q[b][0].z + M[4*t+1]*q[b][1].z + M[4*t+2]*q[b][2].z + M[4*t+3]*q[b][3].z;
            o.w = M[4*t+0]*q[b][0].w + M[4*t+1]*q[b][1].w + M[4*t+2]*q[b][2].w + M[4*t+3]*q[b][3].w;
            po[(size_t)t * ND4] = o;
        }
    }
}

extern "C" void kernel_launch(void* const* d_in, const int* in_sizes, int n_in,
                              void* d_out, int out_size, void* d_ws, size_t ws_size,
                              hipStream_t stream) {
    const f4* in       = (const f4*)d_in[0];
    const float* Hres  = (const float*)d_in[1];
    const float* Hpre  = (const float*)d_in[2];
    const float* Hpost = (const float*)d_in[3];
    f4* out = (f4*)d_out;

    // ND4/256 = 2048 blocks; each thread handles one r across 4 batches.
    hc_mix_kernel<<<ND4 / 256, 256, 0, stream>>>(in, out, Hres, Hpre, Hpost);
}

// Round 10
// 45.736 us; speedup vs baseline: 1.1192x; 1.1192x over previous
//
#include <hip/hip_runtime.h>
#include <math.h>

// HyperConnections: out[(b*S+t), n, d] = sum_s M[t][s] * in[(b*S+s), n, d]
// M[t][s] = sinkhorn(H_res/tau)[s][t] + softmax(H_post)[t] * softmax(H_pre)[s]
//
// B=4, S=4, N=2048, D=1024, fp32. Memory-bound: 128 MiB in + 128 MiB out.
// Structure = R6's best pipeline (batch-0 load hoist, per-batch source-order
// prefetch, 2048 blocks) + R9's barrier-free wave-parallel Sinkhorn (lane
// i*4+j owns element (i,j); LSE reductions via __shfl_xor 1,2 / 4,8).
// No LDS, no __syncthreads, no per-block startup bubble.

#define HC_TAU 0.05f
#define HC_ITERS 10

typedef float f4 __attribute__((ext_vector_type(4)));

// N*D/4 float4 elements per stream = 2048*1024/4 = 524288 = 2^19
constexpr int ND4 = (2048 * 1024) / 4;
constexpr size_t BATCH_STRIDE = (size_t)4 * ND4;   // 4 streams per batch

__global__ __launch_bounds__(256) void hc_mix_kernel(
    const f4* __restrict__ in, f4* __restrict__ out,
    const float* __restrict__ Hres, const float* __restrict__ Hpre,
    const float* __restrict__ Hpost)
{
    const size_t r = (size_t)blockIdx.x * 256 + threadIdx.x;   // 0 .. ND4-1

    // ---- issue batch-0 loads first: overlap HBM latency with preamble ----
    f4 cur0 = in[r];
    f4 cur1 = in[r + ND4];
    f4 cur2 = in[r + 2 * ND4];
    f4 cur3 = in[r + 3 * ND4];

    // ---- wave-parallel Sinkhorn: lane idx = i*4+j owns Z[i][j] ----
    const int lane = threadIdx.x & 63;
    const int idx  = lane & 15;              // replicas in lanes 16-63
    const float Zl = Hres[idx] * (1.0f / HC_TAU);

    float ui = 0.f, vj = 0.f;
    for (int it = 0; it < HC_ITERS; ++it) {
        // u[i] = -lse_j(Z[i][j] + v[j])  -- reduce across row (xor 1,2)
        float x = Zl + vj;
        float m = fmaxf(x, __shfl_xor(x, 1));
        m = fmaxf(m, __shfl_xor(m, 2));
        float e = __expf(x - m);
        float s = e + __shfl_xor(e, 1);
        s += __shfl_xor(s, 2);
        ui = -(m + __logf(s));
        // v[j] = -lse_i(Z[i][j] + u[i])  -- reduce across col (xor 4,8)
        float y = Zl + ui;
        float m2 = fmaxf(y, __shfl_xor(y, 4));
        m2 = fmaxf(m2, __shfl_xor(m2, 8));
        float e2 = __expf(y - m2);
        float s2 = e2 + __shfl_xor(e2, 4);
        s2 += __shfl_xor(s2, 8);
        vj = -(m2 + __logf(s2));
    }
    const float P = __expf(Zl + ui + vj);    // h_res[i][j] on lane i*4+j

    // ---- softmax(H_pre), softmax(H_post): tiny, redundant per lane ----
    float hp[4], bt[4];
    {
        float a0 = Hpre[0], a1 = Hpre[1], a2 = Hpre[2], a3 = Hpre[3];
        float m = fmaxf(fmaxf(a0, a1), fmaxf(a2, a3));
        hp[0] = __expf(a0 - m); hp[1] = __expf(a1 - m);
        hp[2] = __expf(a2 - m); hp[3] = __expf(a3 - m);
        float inv = 1.0f / (hp[0] + hp[1] + hp[2] + hp[3]);
        hp[0] *= inv; hp[1] *= inv; hp[2] *= inv; hp[3] *= inv;

        float b0 = Hpost[0], b1 = Hpost[1], b2 = Hpost[2], b3 = Hpost[3];
        m = fmaxf(fmaxf(b0, b1), fmaxf(b2, b3));
        bt[0] = __expf(b0 - m); bt[1] = __expf(b1 - m);
        bt[2] = __expf(b2 - m); bt[3] = __expf(b3 - m);
        inv = 1.0f / (bt[0] + bt[1] + bt[2] + bt[3]);
        bt[0] *= inv; bt[1] *= inv; bt[2] *= inv; bt[3] *= inv;
    }

    // ---- gather full M into every lane: M[t][s] = P@lane(s*4+t) + bt[t]*hp[s]
    float M[16];
    #pragma unroll
    for (int t = 0; t < 4; ++t)
        #pragma unroll
        for (int s = 0; s < 4; ++s)
            M[t * 4 + s] = __shfl(P, s * 4 + t) + bt[t] * hp[s];

    // ---- 4-batch software pipeline: prefetch b+1, compute/store b ----
    #pragma unroll
    for (int b = 0; b < 4; ++b) {
        f4 n0, n1, n2, n3;
        if (b < 3) {
            const f4* pn = in + (size_t)(b + 1) * BATCH_STRIDE + r;
            n0 = pn[0];
            n1 = pn[ND4];
            n2 = pn[2 * ND4];
            n3 = pn[3 * ND4];
        }

        f4* po = out + (size_t)b * BATCH_STRIDE + r;
        #pragma unroll
        for (int t = 0; t < 4; ++t) {
            f4 o;
            o.x = M[4*t+0]*cur0.x + M[4*t+1]*cur1.x + M[4*t+2]*cur2.x + M[4*t+3]*cur3.x;
            o.y = M[4*t+0]*cur0.y + M[4*t+1]*cur1.y + M[4*t+2]*cur2.y + M[4*t+3]*cur3.y;
            o.z = M[4*t+0]*cur0.z + M[4*t+1]*cur1.z + M[4*t+2]*cur2.z + M[4*t+3]*cur3.z;
            o.w = M[4*t+0]*cur0.w + M[4*t+1]*cur1.w + M[4*t+2]*cur2.w + M[4*t+3]*cur3.w;
            po[(size_t)t * ND4] = o;
        }

        if (b < 3) { cur0 = n0; cur1 = n1; cur2 = n2; cur3 = n3; }
    }
}

extern "C" void kernel_launch(void* const* d_in, const int* in_sizes, int n_in,
                              void* d_out, int out_size, void* d_ws, size_t ws_size,
                              hipStream_t stream) {
    const f4* in       = (const f4*)d_in[0];
    const float* Hres  = (const float*)d_in[1];
    const float* Hpre  = (const float*)d_in[2];
    const float* Hpost = (const float*)d_in[3];
    f4* out = (f4*)d_out;

    // ND4/256 = 2048 blocks; each thread handles one r across 4 batches.
    hc_mix_kernel<<<ND4 / 256, 256, 0, stream>>>(in, out, Hres, Hpre, Hpost);
}